// Round 6
// baseline (822.312 us; speedup 1.0000x reference)
//
#include <hip/hip_runtime.h>
#include <cstdint>

namespace {
constexpr int kNUsers = 50000;
constexpr int kNTotal = 100000;        // N = users + items
constexpr int kD = 64;
constexpr int kHops = 3;
constexpr int kNnz = 3200000;
constexpr int kRowStride = (kHops + 1) * kD;     // 256 floats per node in embs
// packed edge word: col bits 0..16, keep bits 17..19, rowoff bits 20..25
constexpr uint32_t kColMask = (1u << 17) - 1u;
constexpr int kBucketShift = 6;                  // 64 rows per bucket
constexpr int kNBuckets = (kNTotal + 63) >> kBucketShift;   // 1563
constexpr int kBucketCap = 4096;                 // mean 2048, sigma~45 -> safe
constexpr int kScanChunk = 1024;
constexpr int kScanBlocks = (kNTotal + kScanChunk - 1) / kScanChunk;  // 98
}

#define ROTL32(v, r) (((v) << (r)) | ((v) >> (32 - (r))))

// JAX threefry2x32, 20 rounds — matches jax/_src/prng.py exactly.
__host__ __device__ inline void tf2x32(uint32_t k0, uint32_t k1,
                                       uint32_t &x0, uint32_t &x1) {
  const uint32_t k2 = k0 ^ k1 ^ 0x1BD11BDAu;
  x0 += k0; x1 += k1;
#define TFR(r) { x0 += x1; x1 = ROTL32(x1, r); x1 ^= x0; }
  TFR(13) TFR(15) TFR(26) TFR(6)
  x0 += k1; x1 += k2 + 1u;
  TFR(17) TFR(29) TFR(16) TFR(24)
  x0 += k2; x1 += k0 + 2u;
  TFR(13) TFR(15) TFR(26) TFR(6)
  x0 += k0; x1 += k1 + 3u;
  TFR(17) TFR(29) TFR(16) TFR(24)
  x0 += k1; x1 += k2 + 4u;
  TFR(13) TFR(15) TFR(26) TFR(6)
  x0 += k2; x1 += k0 + 5u;
#undef TFR
}

// partitionable random_bits for 32-bit draws: counter (0, i), fold x0^x1
__device__ __forceinline__ uint32_t pbits(uint32_t k0, uint32_t k1, uint32_t i) {
  uint32_t x0 = 0u, x1 = i;
  tf2x32(k0, k1, x0, x1);
  return x0 ^ x1;
}

// bits -> U[0,1) exactly like jax.random.uniform (f32): (b>>9)|0x3f800000, -1.0
__device__ __forceinline__ float u01(uint32_t b) {
  return __uint_as_float((b >> 9) | 0x3f800000u) - 1.0f;
}

// embs[:,0,:] = concat(user, item). One thread per (node, float4).
__global__ void k_init(const float* __restrict__ ue, const float* __restrict__ ie,
                       float* __restrict__ out) {
  int t = blockIdx.x * blockDim.x + threadIdx.x;
  if (t >= kNTotal * 16) return;
  int n = t >> 4, c = t & 15;
  float4 v = (n < kNUsers) ? reinterpret_cast<const float4*>(ue)[n * 16 + c]
                           : reinterpret_cast<const float4*>(ie)[(n - kNUsers) * 16 + c];
  reinterpret_cast<float4*>(out)[(size_t)n * (kRowStride / 4) + c] = v;
}

// ---------------- CSR build ----------------
__global__ void k_zero(int* __restrict__ cnt, int* __restrict__ fill) {
  int t = blockIdx.x * blockDim.x + threadIdx.x;
  if (t < kNTotal) cnt[t] = 0;
  if (t < kNBuckets) fill[t] = 0;
}

__global__ void k_hist(const int* __restrict__ rows, int* __restrict__ cnt) {
  int e = blockIdx.x * blockDim.x + threadIdx.x;
  if (e < kNnz) atomicAdd(&cnt[rows[e]], 1);
}

// scan pass 1: per-block (1024 elems) exclusive scan -> row_ptr; block sum -> bsum
__global__ __launch_bounds__(256) void k_scan1(const int* __restrict__ cnt,
                                               int* __restrict__ row_ptr,
                                               int* __restrict__ bsum) {
  __shared__ int lds[256];
  const int t = threadIdx.x;
  const int base = blockIdx.x * kScanChunk + t * 4;
  int4 c = make_int4(0, 0, 0, 0);
  if (base < kNTotal)                       // kNTotal % 4 == 0, aligned
    c = *reinterpret_cast<const int4*>(cnt + base);
  const int s = c.x + c.y + c.z + c.w;
  lds[t] = s;
  __syncthreads();
  for (int off = 1; off < 256; off <<= 1) {
    int add = (t >= off) ? lds[t - off] : 0;
    __syncthreads();
    lds[t] += add;
    __syncthreads();
  }
  if (base < kNTotal) {
    const int excl = lds[t] - s;
    int4 o;
    o.x = excl;
    o.y = excl + c.x;
    o.z = excl + c.x + c.y;
    o.w = excl + c.x + c.y + c.z;
    *reinterpret_cast<int4*>(row_ptr + base) = o;
  }
  if (t == 255) bsum[blockIdx.x] = lds[255];
}

// scan pass 2: single block scans bsum[kScanBlocks] (exclusive) in LDS
__global__ void k_scan2(int* __restrict__ bsum) {
  __shared__ int lds[128];
  const int t = threadIdx.x;
  int v = (t < kScanBlocks) ? bsum[t] : 0;
  lds[t] = v;
  __syncthreads();
  for (int off = 1; off < 128; off <<= 1) {
    int add = (t >= off) ? lds[t - off] : 0;
    __syncthreads();
    lds[t] += add;
    __syncthreads();
  }
  if (t < kScanBlocks) bsum[t] = lds[t] - v;   // exclusive
}

// scan pass 3: add block offsets; set row_ptr[N]
__global__ __launch_bounds__(256) void k_scan3(int* __restrict__ row_ptr,
                                               const int* __restrict__ bsum) {
  const int t = threadIdx.x;
  const int base = blockIdx.x * kScanChunk + t * 4;
  const int off = bsum[blockIdx.x];
  if (base < kNTotal) {
    int4 o = *reinterpret_cast<int4*>(row_ptr + base);
    o.x += off; o.y += off; o.z += off; o.w += off;
    *reinterpret_cast<int4*>(row_ptr + base) = o;
  }
  if (blockIdx.x == 0 && t == 0) row_ptr[kNTotal] = kNnz;
}

// pass 1: scatter edges into 64-row buckets (in place in csr buffer).
// Appends are dense per bucket -> L2 assembles full lines -> no write amp.
// Entry packs {col | keep3<<17 | rowoff<<20, val*2}; threefry on original e.
__global__ void k_bucket(const int* __restrict__ rows, const int* __restrict__ cols,
                         const float* __restrict__ vals,
                         const int* __restrict__ row_ptr, int* __restrict__ fill,
                         int2* __restrict__ csr,
                         uint32_t ke0_0, uint32_t ke1_0,
                         uint32_t ke0_1, uint32_t ke1_1,
                         uint32_t ke0_2, uint32_t ke1_2) {
  int e = blockIdx.x * blockDim.x + threadIdx.x;
  if (e >= kNnz) return;
  int r = rows[e];
  int b = r >> kBucketShift;
  int pos = row_ptr[b << kBucketShift] + atomicAdd(&fill[b], 1);
  uint32_t x = (uint32_t)cols[e];
  if (u01(pbits(ke0_0, ke1_0, (uint32_t)e)) >= 0.5f) x |= 1u << 17;
  if (u01(pbits(ke0_1, ke1_1, (uint32_t)e)) >= 0.5f) x |= 1u << 18;
  if (u01(pbits(ke0_2, ke1_2, (uint32_t)e)) >= 0.5f) x |= 1u << 19;
  x |= (uint32_t)(r & 63) << 20;
  csr[pos] = make_int2((int)x, __float_as_int(vals[e] * 2.0f));
}

// pass 2: one block per bucket. Load bucket into LDS (all reads complete),
// barrier, then place each entry at its final row position (in place).
// Writes span only the bucket's ~32 KB region -> L2-resident, no write amp.
__global__ __launch_bounds__(256) void k_permute(const int* __restrict__ row_ptr,
                                                 const int* __restrict__ fill,
                                                 int2* __restrict__ csr) {
  __shared__ int2 st[kBucketCap];
  __shared__ int lcnt[64];
  const int b = blockIdx.x;
  const int row0 = b << kBucketShift;
  const int base = row_ptr[row0];
  const int n = fill[b];                   // <= kBucketCap (mean+45 sigma)
  if (threadIdx.x < 64) lcnt[threadIdx.x] = 0;
  for (int i = threadIdx.x; i < n; i += 256) st[i] = csr[base + i];
  __syncthreads();
  for (int i = threadIdx.x; i < n; i += 256) {
    int2 v = st[i];
    int rowoff = (int)(((uint32_t)v.x >> 20) & 63u);
    int pos = row_ptr[row0 + rowoff] + atomicAdd(&lcnt[rowoff], 1);
    csr[pos] = v;
  }
}

// ---------------- fused SpMM: one wave per row ----------------
__global__ __launch_bounds__(256) void k_spmm_csr(
    const int* __restrict__ row_ptr, const int2* __restrict__ csr,
    const float* __restrict__ src, float* __restrict__ dst,
    uint32_t hopbit, uint32_t km0, uint32_t km1) {
  __shared__ int2 stage[4][68];
  const int wave = threadIdx.x >> 6;
  const int lane = threadIdx.x & 63;
  const int r = __builtin_amdgcn_readfirstlane(blockIdx.x * 4 + wave);
  if (r >= kNTotal) return;
  const int start = row_ptr[r], end = row_ptr[r + 1];
  float a0 = 0.f, a1 = 0.f, a2 = 0.f, a3 = 0.f;
  for (int base = start; base < end; base += 64) {
    const int n = min(64, end - base);
    bool keep = false;
    int2 cv = make_int2(0, 0);
    if (lane < n) {
      cv = csr[base + lane];
      keep = ((uint32_t)cv.x & hopbit) != 0u;
    }
    const uint64_t m = __ballot(keep);
    const int k = __popcll(m);
    if (keep) {
      const int slot = __popcll(m & ((1ull << lane) - 1ull));
      stage[wave][slot] = make_int2((int)((uint32_t)cv.x & kColMask), cv.y);
    }
    if (lane < 3) stage[wave][k + lane] = make_int2(0, 0);  // zero-pad for unroll tail
    for (int j = 0; j < k; j += 4) {
      const int2 e0 = stage[wave][j];
      const int2 e1 = stage[wave][j + 1];
      const int2 e2 = stage[wave][j + 2];
      const int2 e3 = stage[wave][j + 3];
      a0 += __int_as_float(e0.y) * src[(size_t)e0.x * kRowStride + lane];
      a1 += __int_as_float(e1.y) * src[(size_t)e1.x * kRowStride + lane];
      a2 += __int_as_float(e2.y) * src[(size_t)e2.x * kRowStride + lane];
      a3 += __int_as_float(e3.y) * src[(size_t)e3.x * kRowStride + lane];
    }
  }
  const float acc = (a0 + a1) + (a2 + a3);
  const float u = u01(pbits(km0, km1, (uint32_t)(r * 64 + lane)));
  dst[(size_t)r * kRowStride + lane] = (u < 0.9f) ? acc * (float)(1.0 / 0.9) : 0.0f;
}

extern "C" void kernel_launch(void* const* d_in, const int* in_sizes, int n_in,
                              void* d_out, int out_size, void* d_ws, size_t ws_size,
                              hipStream_t stream) {
  const float* ue = (const float*)d_in[0];
  const float* ie = (const float*)d_in[1];
  const float* ev = (const float*)d_in[2];
  const int*   er = (const int*)d_in[3];
  const int*   ec = (const int*)d_in[4];
  float* out = (float*)d_out;

  // keys: base = key(42) = (0,42); per hop fold_in, then partitionable split:
  // keys[j] = threefry(folded_key, (0, j)).
  uint32_t ke0[kHops], ke1[kHops], km0[kHops], km1[kHops];
  for (int hop = 0; hop < kHops; ++hop) {
    uint32_t f0 = 0u, f1 = (uint32_t)hop;
    tf2x32(0u, 42u, f0, f1);
    uint32_t e0 = 0u, e1 = 0u;
    tf2x32(f0, f1, e0, e1);
    uint32_t m0 = 0u, m1 = 1u;
    tf2x32(f0, f1, m0, m1);
    ke0[hop] = e0; ke1[hop] = e1;
    km0[hop] = m0; km1[hop] = m1;
  }

  const int BS = 256;

  // ws layout (int units):
  // row_ptr[100001] | cnt[100000] | bsum[98] | fill[1563] | pad | csr int2[NNZ]
  const size_t off_rowptr = 0;
  const size_t off_cnt    = 100001;
  const size_t off_bsum   = 200001;
  const size_t off_fill   = 200099;
  const size_t off_csr    = 201664;                 // 16B aligned (*4B)
  int*  row_ptr = (int*)d_ws + off_rowptr;
  int*  cnt     = (int*)d_ws + off_cnt;
  int*  bsum    = (int*)d_ws + off_bsum;
  int*  fill    = (int*)d_ws + off_fill;
  int2* csr     = (int2*)((int*)d_ws + off_csr);

  k_init<<<(kNTotal * 16 + BS - 1) / BS, BS, 0, stream>>>(ue, ie, out);
  k_zero<<<(kNTotal + BS - 1) / BS, BS, 0, stream>>>(cnt, fill);
  k_hist<<<(kNnz + BS - 1) / BS, BS, 0, stream>>>(er, cnt);
  k_scan1<<<kScanBlocks, 256, 0, stream>>>(cnt, row_ptr, bsum);
  k_scan2<<<1, 128, 0, stream>>>(bsum);
  k_scan3<<<kScanBlocks, 256, 0, stream>>>(row_ptr, bsum);
  k_bucket<<<(kNnz + BS - 1) / BS, BS, 0, stream>>>(
      er, ec, ev, row_ptr, fill, csr,
      ke0[0], ke1[0], ke0[1], ke1[1], ke0[2], ke1[2]);
  k_permute<<<kNBuckets, 256, 0, stream>>>(row_ptr, fill, csr);

  for (int hop = 0; hop < kHops; ++hop) {
    const float* src = out + (size_t)hop * kD;
    float*       dst = out + (size_t)(hop + 1) * kD;
    k_spmm_csr<<<(kNTotal + 3) / 4, 256, 0, stream>>>(
        row_ptr, csr, src, dst, 1u << (17 + hop), km0[hop], km1[hop]);
  }
}

// Round 7
// 295.419 us; speedup vs baseline: 2.7835x; 2.7835x over previous
//
#include <hip/hip_runtime.h>
#include <cstdint>

namespace {
constexpr int kNUsers = 50000;
constexpr int kNTotal = 100000;        // N = users + items
constexpr int kD = 64;
constexpr int kHops = 3;
constexpr int kNnz = 3200000;
constexpr int kRowStride = (kHops + 1) * kD;     // 256 floats per node in embs
// packed edge word: col bits 0..16, keep bits 17..19, rowoff bits 20..26
constexpr uint32_t kColMask = (1u << 17) - 1u;
constexpr int kSBShift = 7;                      // 128 rows per super-bucket
constexpr int kSBRows = 1 << kSBShift;
constexpr int kNSB = (kNTotal + kSBRows - 1) / kSBRows;       // 782
constexpr int kSBCap = 5120;      // mean 4092, sigma 64 -> +16 sigma, fixed dataset
constexpr int kP1Batch = 4096;                   // edges per split1 block
constexpr int kP1Blocks = (kNnz + kP1Batch - 1) / kP1Batch;   // 782
}

#define ROTL32(v, r) (((v) << (r)) | ((v) >> (32 - (r))))

// JAX threefry2x32, 20 rounds — matches jax/_src/prng.py exactly.
__host__ __device__ inline void tf2x32(uint32_t k0, uint32_t k1,
                                       uint32_t &x0, uint32_t &x1) {
  const uint32_t k2 = k0 ^ k1 ^ 0x1BD11BDAu;
  x0 += k0; x1 += k1;
#define TFR(r) { x0 += x1; x1 = ROTL32(x1, r); x1 ^= x0; }
  TFR(13) TFR(15) TFR(26) TFR(6)
  x0 += k1; x1 += k2 + 1u;
  TFR(17) TFR(29) TFR(16) TFR(24)
  x0 += k2; x1 += k0 + 2u;
  TFR(13) TFR(15) TFR(26) TFR(6)
  x0 += k0; x1 += k1 + 3u;
  TFR(17) TFR(29) TFR(16) TFR(24)
  x0 += k1; x1 += k2 + 4u;
  TFR(13) TFR(15) TFR(26) TFR(6)
  x0 += k2; x1 += k0 + 5u;
#undef TFR
}

// partitionable random_bits for 32-bit draws: counter (0, i), fold x0^x1
__device__ __forceinline__ uint32_t pbits(uint32_t k0, uint32_t k1, uint32_t i) {
  uint32_t x0 = 0u, x1 = i;
  tf2x32(k0, k1, x0, x1);
  return x0 ^ x1;
}

// bits -> U[0,1) exactly like jax.random.uniform (f32): (b>>9)|0x3f800000, -1.0
__device__ __forceinline__ float u01(uint32_t b) {
  return __uint_as_float((b >> 9) | 0x3f800000u) - 1.0f;
}

// embs[:,0,:] = concat(user, item). One thread per (node, float4). Zeros tail[].
__global__ void k_init(const float* __restrict__ ue, const float* __restrict__ ie,
                       float* __restrict__ out, int* __restrict__ tail) {
  int t = blockIdx.x * blockDim.x + threadIdx.x;
  if (t < kNSB) tail[t] = 0;
  if (t >= kNTotal * 16) return;
  int n = t >> 4, c = t & 15;
  float4 v = (n < kNUsers) ? reinterpret_cast<const float4*>(ue)[n * 16 + c]
                           : reinterpret_cast<const float4*>(ie)[(n - kNUsers) * 16 + c];
  reinterpret_cast<float4*>(out)[(size_t)n * (kRowStride / 4) + c] = v;
}

// ---------------- multisplit pass 1: block-aggregated bucket append ----------------
// Each block: LDS histogram over 782 buckets for its 4096 edges, ONE global
// atomicAdd per (block,bucket) to reserve a contiguous chunk, then write its
// edges contiguously into the chunk. A stage cache line is written by exactly
// one block (except chunk boundaries) -> full-line assembly, no XCD ping-pong.
__global__ __launch_bounds__(256) void k_split1(
    const int* __restrict__ er, const int* __restrict__ ec,
    const float* __restrict__ ev, int* __restrict__ tail,
    int2* __restrict__ stage,
    uint32_t ke0_0, uint32_t ke1_0, uint32_t ke0_1, uint32_t ke1_1,
    uint32_t ke0_2, uint32_t ke1_2) {
  __shared__ int hist[kNSB];
  __shared__ int base[kNSB];
  const int t = threadIdx.x;
  const int e0 = blockIdx.x * kP1Batch;
  const int n = min(kP1Batch, kNnz - e0);
  for (int i = t; i < kNSB; i += 256) hist[i] = 0;
  __syncthreads();
  for (int i = t; i < n; i += 256)
    atomicAdd(&hist[(uint32_t)er[e0 + i] >> kSBShift], 1);
  __syncthreads();
  for (int i = t; i < kNSB; i += 256) {
    const int c = hist[i];
    base[i] = (c > 0) ? atomicAdd(&tail[i], c) : 0;
    hist[i] = 0;                     // reuse as cursor
  }
  __syncthreads();
  for (int i = t; i < n; i += 256) {
    const int e = e0 + i;
    const int r = er[e];
    const int b = (uint32_t)r >> kSBShift;
    const int pos = base[b] + atomicAdd(&hist[b], 1);
    if (pos < kSBCap) {              // 16-sigma guard; never triggers
      uint32_t x = (uint32_t)ec[e];
      if (u01(pbits(ke0_0, ke1_0, (uint32_t)e)) >= 0.5f) x |= 1u << 17;
      if (u01(pbits(ke0_1, ke1_1, (uint32_t)e)) >= 0.5f) x |= 1u << 18;
      if (u01(pbits(ke0_2, ke1_2, (uint32_t)e)) >= 0.5f) x |= 1u << 19;
      x |= (uint32_t)(r & (kSBRows - 1)) << 20;
      stage[(size_t)b * kSBCap + pos] = make_int2((int)x, __float_as_int(ev[e] * 2.0f));
    }
  }
}

// ---------------- multisplit pass 2: per-bucket row sort (in place) ----------------
// One block per super-bucket: load all entries to LDS (reads complete before any
// write), LDS histogram+scan over 128 rows, emit row_start/row_len, place entries
// row-sorted within the block's private region. Single-XCD full-line writes.
__global__ __launch_bounds__(256) void k_split2(
    const int* __restrict__ tail, int2* __restrict__ stage,
    int* __restrict__ row_start, int* __restrict__ row_len) {
  __shared__ int2 st[kSBCap];        // 40 KB
  __shared__ int lcnt[kSBRows], lsc[kSBRows], lcur[kSBRows];
  const int b = blockIdx.x;
  const int t = threadIdx.x;
  const int row0 = b << kSBShift;
  const int nrows = min(kSBRows, kNTotal - row0);
  const int n = min(tail[b], kSBCap);
  int2* reg = stage + (size_t)b * kSBCap;
  if (t < kSBRows) { lcnt[t] = 0; lcur[t] = 0; }
  for (int i = t; i < n; i += 256) st[i] = reg[i];
  __syncthreads();
  for (int i = t; i < n; i += 256)
    atomicAdd(&lcnt[((uint32_t)st[i].x >> 20) & (kSBRows - 1u)], 1);
  __syncthreads();
  if (t < kSBRows) lsc[t] = lcnt[t];
  __syncthreads();
  for (int off = 1; off < kSBRows; off <<= 1) {   // Hillis-Steele inclusive
    int add = (t >= off && t < kSBRows) ? lsc[t - off] : 0;
    __syncthreads();
    if (t < kSBRows) lsc[t] += add;
    __syncthreads();
  }
  if (t < nrows) {
    const int excl = lsc[t] - lcnt[t];
    row_start[row0 + t] = b * kSBCap + excl;
    row_len[row0 + t] = lcnt[t];
  }
  __syncthreads();
  for (int i = t; i < n; i += 256) {
    const int2 v = st[i];
    const int r = (int)(((uint32_t)v.x >> 20) & (kSBRows - 1u));
    const int pos = (lsc[r] - lcnt[r]) + atomicAdd(&lcur[r], 1);
    reg[pos] = v;
  }
}

// ---------------- fused SpMM: one wave per row ----------------
__global__ __launch_bounds__(256) void k_spmm_csr(
    const int* __restrict__ row_start, const int* __restrict__ row_len,
    const int2* __restrict__ csr,
    const float* __restrict__ src, float* __restrict__ dst,
    uint32_t hopbit, uint32_t km0, uint32_t km1) {
  __shared__ int2 stage[4][68];
  const int wave = threadIdx.x >> 6;
  const int lane = threadIdx.x & 63;
  const int r = __builtin_amdgcn_readfirstlane(blockIdx.x * 4 + wave);
  if (r >= kNTotal) return;
  const int start = row_start[r];
  const int end = start + row_len[r];
  float a0 = 0.f, a1 = 0.f, a2 = 0.f, a3 = 0.f;
  for (int base = start; base < end; base += 64) {
    const int n = min(64, end - base);
    bool keep = false;
    int2 cv = make_int2(0, 0);
    if (lane < n) {
      cv = csr[base + lane];
      keep = ((uint32_t)cv.x & hopbit) != 0u;
    }
    const uint64_t m = __ballot(keep);
    const int k = __popcll(m);
    if (keep) {
      const int slot = __popcll(m & ((1ull << lane) - 1ull));
      stage[wave][slot] = make_int2((int)((uint32_t)cv.x & kColMask), cv.y);
    }
    if (lane < 3) stage[wave][k + lane] = make_int2(0, 0);  // zero-pad for unroll tail
    for (int j = 0; j < k; j += 4) {
      const int2 e0 = stage[wave][j];
      const int2 e1 = stage[wave][j + 1];
      const int2 e2 = stage[wave][j + 2];
      const int2 e3 = stage[wave][j + 3];
      a0 += __int_as_float(e0.y) * src[(size_t)e0.x * kRowStride + lane];
      a1 += __int_as_float(e1.y) * src[(size_t)e1.x * kRowStride + lane];
      a2 += __int_as_float(e2.y) * src[(size_t)e2.x * kRowStride + lane];
      a3 += __int_as_float(e3.y) * src[(size_t)e3.x * kRowStride + lane];
    }
  }
  const float acc = (a0 + a1) + (a2 + a3);
  const float u = u01(pbits(km0, km1, (uint32_t)(r * 64 + lane)));
  dst[(size_t)r * kRowStride + lane] = (u < 0.9f) ? acc * (float)(1.0 / 0.9) : 0.0f;
}

extern "C" void kernel_launch(void* const* d_in, const int* in_sizes, int n_in,
                              void* d_out, int out_size, void* d_ws, size_t ws_size,
                              hipStream_t stream) {
  const float* ue = (const float*)d_in[0];
  const float* ie = (const float*)d_in[1];
  const float* ev = (const float*)d_in[2];
  const int*   er = (const int*)d_in[3];
  const int*   ec = (const int*)d_in[4];
  float* out = (float*)d_out;

  // keys: base = key(42) = (0,42); per hop fold_in, then partitionable split:
  // keys[j] = threefry(folded_key, (0, j)).
  uint32_t ke0[kHops], ke1[kHops], km0[kHops], km1[kHops];
  for (int hop = 0; hop < kHops; ++hop) {
    uint32_t f0 = 0u, f1 = (uint32_t)hop;
    tf2x32(0u, 42u, f0, f1);
    uint32_t e0 = 0u, e1 = 0u;
    tf2x32(f0, f1, e0, e1);
    uint32_t m0 = 0u, m1 = 1u;
    tf2x32(f0, f1, m0, m1);
    ke0[hop] = e0; ke1[hop] = e1;
    km0[hop] = m0; km1[hop] = m1;
  }

  const int BS = 256;

  // ws layout (int units):
  // row_start[100000] | row_len[100000] | tail[782] | pad | stage int2[782*5120]
  const size_t off_rowstart = 0;
  const size_t off_rowlen   = 100000;
  const size_t off_tail     = 200000;
  const size_t off_stage    = 200784;              // *4B = 803136, 16B aligned
  int*  row_start = (int*)d_ws + off_rowstart;
  int*  row_len   = (int*)d_ws + off_rowlen;
  int*  tail      = (int*)d_ws + off_tail;
  int2* stage     = (int2*)((int*)d_ws + off_stage);

  k_init<<<(kNTotal * 16 + BS - 1) / BS, BS, 0, stream>>>(ue, ie, out, tail);
  k_split1<<<kP1Blocks, 256, 0, stream>>>(
      er, ec, ev, tail, stage,
      ke0[0], ke1[0], ke0[1], ke1[1], ke0[2], ke1[2]);
  k_split2<<<kNSB, 256, 0, stream>>>(tail, stage, row_start, row_len);

  for (int hop = 0; hop < kHops; ++hop) {
    const float* src = out + (size_t)hop * kD;
    float*       dst = out + (size_t)(hop + 1) * kD;
    k_spmm_csr<<<(kNTotal + 3) / 4, 256, 0, stream>>>(
        row_start, row_len, stage, src, dst, 1u << (17 + hop), km0[hop], km1[hop]);
  }
}